// Round 1
// baseline (226.601 us; speedup 1.0000x reference)
//
#include <hip/hip_runtime.h>

typedef __bf16 bf16x8 __attribute__((ext_vector_type(8)));
typedef short short8 __attribute__((ext_vector_type(8)));
typedef float f32x4 __attribute__((ext_vector_type(4)));

// B=8, T=2048, E=512, H=8, d=64
#define TT 2048
#define EE 512
#define NH 8
#define DD 64

__device__ __forceinline__ ushort f2bf(float f) {
  union { float f; unsigned u; } a; a.f = f;
  unsigned u = a.u;
  return (ushort)((u + 0x7FFFu + ((u >> 16) & 1u)) >> 16);  // RNE
}
__device__ __forceinline__ float bf2f(ushort b) {
  union { unsigned u; float f; } a; a.u = ((unsigned)b) << 16;
  return a.f;
}

// ---------------- Kernel 1: LayerNorm + Q,K scalars + V (per token) --------
// grid = B*T blocks, 512 threads (8 waves = 8 heads)
__global__ __launch_bounds__(512) void k_ln_qkv(
    const float* __restrict__ x, const float* __restrict__ Wq,
    const float* __restrict__ Wk, const float* __restrict__ Wv,
    float* __restrict__ Q, float* __restrict__ K, ushort* __restrict__ V) {
  const int bt = blockIdx.x;
  const int tid = threadIdx.x;
  const int lane = tid & 63, wid = tid >> 6;
  __shared__ float xs[512];
  __shared__ float red[16];

  float v = x[(size_t)bt * EE + tid];
  float s = v, s2 = v * v;
#pragma unroll
  for (int o = 32; o; o >>= 1) { s += __shfl_xor(s, o); s2 += __shfl_xor(s2, o); }
  if (lane == 0) { red[wid] = s; red[8 + wid] = s2; }
  __syncthreads();
  float ts = 0.f, ts2 = 0.f;
#pragma unroll
  for (int i = 0; i < 8; i++) { ts += red[i]; ts2 += red[8 + i]; }
  const float mean = ts * (1.f / 512.f);
  const float var = ts2 * (1.f / 512.f) - mean * mean;
  const float rstd = rsqrtf(var + 1e-5f);
  const float xn = (v - mean) * rstd;
  xs[tid] = xn;
  __syncthreads();

  // wave `wid` owns head h = wid; tid = h*64 + lane indexes Wq/Wk flat
  float q = xn * Wq[tid];
  float k = xn * Wk[tid];
#pragma unroll
  for (int o = 32; o; o >>= 1) { q += __shfl_xor(q, o); k += __shfl_xor(k, o); }
  const int b = bt >> 11, t = bt & (TT - 1);
  const int bh = b * NH + wid;
  if (lane == 0) { Q[bh * TT + t] = q; K[bh * TT + t] = k; }

  // V[b,h,t,e] = sum_d xn[h*64+d] * Wv[h,d,e]; lane = e
  const float* Wvh = Wv + wid * (DD * DD);
  const float* xh = xs + wid * DD;
  float acc = 0.f;
#pragma unroll 8
  for (int dd = 0; dd < DD; dd++) acc = fmaf(xh[dd], Wvh[dd * DD + lane], acc);
  V[((size_t)bh * TT + t) * DD + lane] = f2bf(acc);
}

// ---------------- Kernel 2: Wm (f32 [K][N]) -> Wmt (bf16 [N][K]) -----------
__global__ __launch_bounds__(256) void k_prep(const float* __restrict__ Wm,
                                              ushort* __restrict__ Wmt) {
  int idx = blockIdx.x * 256 + threadIdx.x;  // idx = n*512 + k
  int n = idx >> 9, k = idx & 511;
  Wmt[idx] = f2bf(Wm[k * EE + n]);
}

// ---------------- Kernel 3: distance attention, MFMA P@V -------------------
// grid = (T/128, B*H); 256 threads (4 waves, 32 queries each)
__global__ __launch_bounds__(256) void k_attn(
    const float* __restrict__ Q, const float* __restrict__ K,
    const ushort* __restrict__ V, ushort* __restrict__ hr) {
  const int bh = blockIdx.y;
  const int q0 = blockIdx.x * 128;
  const int tid = threadIdx.x;
  const int w = tid >> 6, l = tid & 63;
  const int l16 = l & 15, lhi = l >> 4;

  __shared__ float ks[TT];
  __shared__ float qs[128];
  __shared__ ushort vt[64 * 72];  // [e][72] bf16, row stride 144B, 16B-chunk XOR swizzle

  const float* Kb = K + bh * TT;
#pragma unroll
  for (int i = 0; i < 8; i++) ks[tid + i * 256] = Kb[tid + i * 256];
  if (tid < 128) qs[tid] = Q[bh * TT + q0 + tid];
  __syncthreads();

  const float qv0 = qs[w * 32 + l16];
  const float qv1 = qs[w * 32 + 16 + l16];
  f32x4 acc[2][4];
#pragma unroll
  for (int g = 0; g < 2; g++)
#pragma unroll
    for (int c = 0; c < 4; c++) acc[g][c] = (f32x4){0.f, 0.f, 0.f, 0.f};
  float lsum0 = 0.f, lsum1 = 0.f;

  const ushort* Vb = V + (size_t)bh * (TT * DD);
  const int j0 = (tid >> 3) * 2;       // 0..62 (even)
  const int e0 = (tid & 7) * 8;        // 0..56

  for (int jt = 0; jt < TT; jt += 64) {
    __syncthreads();
    // stage V tile [64j][64e] -> vt[e][j] (transposed, swizzled), u32 j-pair writes
    const ushort* src = Vb + (size_t)(jt + j0) * DD + e0;
    union { uint4 v; ushort u[8]; } a0, a1;
    a0.v = *(const uint4*)src;
    a1.v = *(const uint4*)(src + DD);
#pragma unroll
    for (int i = 0; i < 8; i++) {
      int e = e0 + i;
      int off = ((j0 * 2) ^ (((e >> 3) & 7) << 4)) >> 1;  // ushort offset within row
      unsigned pack = (unsigned)a0.u[i] | ((unsigned)a1.u[i] << 16);
      *(unsigned*)&vt[e * 72 + off] = pack;
    }
    __syncthreads();

#pragma unroll
    for (int kk = 0; kk < 2; kk++) {
      // B fragments: V[j][e], col e = c*16+l16, k-chunk = lhi*8 (+i contiguous)
      bf16x8 vf[4];
#pragma unroll
      for (int c = 0; c < 4; c++) {
        int e = c * 16 + l16;
        int offb = ((kk * 64 + lhi * 16) ^ (((e >> 3) & 7) << 4)) >> 1;
        vf[c] = *(const bf16x8*)&vt[e * 72 + offb];
      }
      const int jb = jt + kk * 32 + lhi * 8;
      float4 ka = *(const float4*)&ks[jb];
      float4 kb = *(const float4*)&ks[jb + 4];
      float kv[8] = {ka.x, ka.y, ka.z, ka.w, kb.x, kb.y, kb.z, kb.w};
#pragma unroll
      for (int g = 0; g < 2; g++) {
        const float qv = g ? qv1 : qv0;
        short8 pf;
        float psum = 0.f;
#pragma unroll
        for (int i = 0; i < 8; i++) {
          float dq = qv - kv[i];
          // exp(-(dq^2)/8) = exp2(dq^2 * -0.125*log2(e))
          float p = exp2f(dq * dq * -0.18033688f);
          ushort pb = f2bf(p);
          psum += bf2f(pb);  // denominator from the same rounded p as numerator
          pf[i] = (short)pb;
        }
        if (g) lsum1 += psum; else lsum0 += psum;
        bf16x8 pa = __builtin_bit_cast(bf16x8, pf);
#pragma unroll
        for (int c = 0; c < 4; c++)
          acc[g][c] = __builtin_amdgcn_mfma_f32_16x16x32_bf16(pa, vf[c], acc[g][c], 0, 0, 0);
      }
    }
  }

  // row sums: A-layout rows are l16, spread over the 4 lhi groups
  lsum0 += __shfl_xor(lsum0, 16); lsum0 += __shfl_xor(lsum0, 32);
  lsum1 += __shfl_xor(lsum1, 16); lsum1 += __shfl_xor(lsum1, 32);

  const int b = bh >> 3, h = bh & 7;
#pragma unroll
  for (int g = 0; g < 2; g++) {
#pragma unroll
    for (int r = 0; r < 4; r++) {
      // C/D layout: row = lhi*4 + r, col = l16 (verified)
      float rs = __shfl(g ? lsum1 : lsum0, lhi * 4 + r);
      float rinv = 1.f / rs;
      int qrow = q0 + w * 32 + g * 16 + lhi * 4 + r;
      size_t base = ((size_t)(b * TT + qrow)) * EE + h * DD + l16;
#pragma unroll
      for (int c = 0; c < 4; c++)
        hr[base + c * 16] = f2bf(acc[g][c][r] * rinv);
    }
  }
}

// ---------------- Kernel 4: out = hr @ Wm + x  (bf16 MFMA GEMM) ------------
// grid = (N/128=4, M/128=128); 256 threads (4 waves, 2x2 wave grid, 64x64 each)
__global__ __launch_bounds__(256) void k_merge(
    const ushort* __restrict__ hr, const ushort* __restrict__ Wmt,
    const float* __restrict__ x, float* __restrict__ out) {
  const int n0 = blockIdx.x * 128;
  const int m0 = blockIdx.y * 128;
  const int tid = threadIdx.x;
  const int w = tid >> 6, l = tid & 63;
  const int l16 = l & 15, lhi = l >> 4;
  const int wm = w >> 1, wn = w & 1;

  __shared__ ushort As[128 * 72];
  __shared__ ushort Bs[128 * 72];
  f32x4 acc[4][4];
#pragma unroll
  for (int i = 0; i < 4; i++)
#pragma unroll
    for (int j = 0; j < 4; j++) acc[i][j] = (f32x4){0.f, 0.f, 0.f, 0.f};

  const int row = tid >> 1, half = tid & 1;
  for (int k0 = 0; k0 < EE; k0 += 64) {
    __syncthreads();
    {
      const ushort* sa = hr + (size_t)(m0 + row) * EE + k0 + half * 32;
      const ushort* sb = Wmt + (size_t)(n0 + row) * EE + k0 + half * 32;
      uint4* da = (uint4*)&As[row * 72 + half * 32];
      uint4* db = (uint4*)&Bs[row * 72 + half * 32];
#pragma unroll
      for (int i = 0; i < 4; i++) da[i] = *(const uint4*)(sa + i * 8);
#pragma unroll
      for (int i = 0; i < 4; i++) db[i] = *(const uint4*)(sb + i * 8);
    }
    __syncthreads();
#pragma unroll
    for (int kk = 0; kk < 2; kk++) {
      bf16x8 af[4], bfr[4];
#pragma unroll
      for (int mi = 0; mi < 4; mi++)
        af[mi] = *(const bf16x8*)&As[(wm * 64 + mi * 16 + l16) * 72 + kk * 32 + lhi * 8];
#pragma unroll
      for (int ni = 0; ni < 4; ni++)
        bfr[ni] = *(const bf16x8*)&Bs[(wn * 64 + ni * 16 + l16) * 72 + kk * 32 + lhi * 8];
#pragma unroll
      for (int mi = 0; mi < 4; mi++)
#pragma unroll
        for (int ni = 0; ni < 4; ni++)
          acc[mi][ni] = __builtin_amdgcn_mfma_f32_16x16x32_bf16(af[mi], bfr[ni], acc[mi][ni], 0, 0, 0);
    }
  }

#pragma unroll
  for (int mi = 0; mi < 4; mi++) {
#pragma unroll
    for (int r = 0; r < 4; r++) {
      const int grow = m0 + wm * 64 + mi * 16 + lhi * 4 + r;
#pragma unroll
      for (int ni = 0; ni < 4; ni++) {
        const int gcol = n0 + wn * 64 + ni * 16 + l16;
        size_t idx = (size_t)grow * EE + gcol;
        out[idx] = acc[mi][ni][r] + x[idx];
      }
    }
  }
}

// ---------------- launch ----------------------------------------------------
extern "C" void kernel_launch(void* const* d_in, const int* in_sizes, int n_in,
                              void* d_out, int out_size, void* d_ws, size_t ws_size,
                              hipStream_t stream) {
  const float* x  = (const float*)d_in[0];
  const float* Wq = (const float*)d_in[1];
  const float* Wk = (const float*)d_in[2];
  const float* Wv = (const float*)d_in[3];
  const float* Wm = (const float*)d_in[4];
  float* out = (float*)d_out;

  char* ws = (char*)d_ws;
  // layout: Q f32 [64][2048] | K f32 | V bf16 [64][2048][64] | hr bf16 [16384][512] | Wmt bf16 [512][512]
  float*  Qp  = (float*)(ws);
  float*  Kp  = (float*)(ws + 524288);
  ushort* Vp  = (ushort*)(ws + 1048576);
  ushort* hrp = (ushort*)(ws + 17825792);
  ushort* Wmt = (ushort*)(ws + 34603008);

  k_ln_qkv<<<8 * TT, 512, 0, stream>>>(x, Wq, Wk, Wv, Qp, Kp, Vp);
  k_prep<<<(EE * EE) / 256, 256, 0, stream>>>(Wm, Wmt);
  k_attn<<<dim3(TT / 128, 8 * NH), 256, 0, stream>>>(Qp, Kp, Vp, hrp);
  k_merge<<<dim3(EE / 128, (8 * TT) / 128), 256, 0, stream>>>(hrp, Wmt, x, out);
}

// Round 2
// 172.983 us; speedup vs baseline: 1.3100x; 1.3100x over previous
//
#include <hip/hip_runtime.h>

typedef __bf16 bf16x8 __attribute__((ext_vector_type(8)));
typedef short short8 __attribute__((ext_vector_type(8)));
typedef float f32x4 __attribute__((ext_vector_type(4)));

// B=8, T=2048, E=512, H=8, d=64
#define TT 2048
#define EE 512
#define NH 8
#define DD 64

#define QSCALE 0.36067376022224085f   // 0.25 * log2(e)
#define CSCALE 0.18033688011112042f   // 0.125 * log2(e)

__device__ __forceinline__ ushort f2bf(float f) {
  union { float f; unsigned u; } a; a.f = f;
  unsigned u = a.u;
  return (ushort)((u + 0x7FFFu + ((u >> 16) & 1u)) >> 16);  // RNE
}

// ---------------- Kernel 1: LayerNorm + Q',K scalars + xn (bf16) -----------
// grid = B*T blocks, 512 threads (8 waves = 8 heads)
__global__ __launch_bounds__(512) void k_ln(
    const float* __restrict__ x, const float* __restrict__ Wq,
    const float* __restrict__ Wk,
    float* __restrict__ Q, float* __restrict__ K, ushort* __restrict__ xnb) {
  const int bt = blockIdx.x;
  const int tid = threadIdx.x;
  const int lane = tid & 63, wid = tid >> 6;
  __shared__ float red[16];

  float v = x[(size_t)bt * EE + tid];
  float s = v, s2 = v * v;
#pragma unroll
  for (int o = 32; o; o >>= 1) { s += __shfl_xor(s, o); s2 += __shfl_xor(s2, o); }
  if (lane == 0) { red[wid] = s; red[8 + wid] = s2; }
  __syncthreads();
  float ts = 0.f, ts2 = 0.f;
#pragma unroll
  for (int i = 0; i < 8; i++) { ts += red[i]; ts2 += red[8 + i]; }
  const float mean = ts * (1.f / 512.f);
  const float var = ts2 * (1.f / 512.f) - mean * mean;
  const float rstd = rsqrtf(var + 1e-5f);
  const float xn = (v - mean) * rstd;
  xnb[(size_t)bt * EE + tid] = f2bf(xn);

  // wave `wid` owns head h = wid; tid = h*64 + lane indexes Wq/Wk flat
  float q = xn * Wq[tid];
  float k = xn * Wk[tid];
#pragma unroll
  for (int o = 32; o; o >>= 1) { q += __shfl_xor(q, o); k += __shfl_xor(k, o); }
  const int b = bt >> 11, t = bt & (TT - 1);
  const int bh = b * NH + wid;
  if (lane == 0) { Q[bh * TT + t] = q * QSCALE; K[bh * TT + t] = k; }
}

// ---------------- Kernel 2: Wvmt[n][k] = (Wv_h @ Wm_h)^T, bf16 -------------
// Wvm[k=h*64+d][n] = sum_e Wv[k*64+e] * Wm[(h*64+e)*512+n]; grid=512, 256 thr
__global__ __launch_bounds__(256) void k_wvm(
    const float* __restrict__ Wv, const float* __restrict__ Wm,
    ushort* __restrict__ Wvmt) {
  const int n = blockIdx.x;
  const int tid = threadIdx.x;
  const int k0 = tid, k1 = tid + 256;
  const int h0 = k0 >> 6, h1 = k1 >> 6;
  float acc0 = 0.f, acc1 = 0.f;
#pragma unroll 8
  for (int e = 0; e < 64; e++) {
    acc0 = fmaf(Wv[k0 * 64 + e], Wm[(h0 * 64 + e) * EE + n], acc0);
    acc1 = fmaf(Wv[k1 * 64 + e], Wm[(h1 * 64 + e) * EE + n], acc1);
  }
  Wvmt[n * EE + k0] = f2bf(acc0);
  Wvmt[n * EE + k1] = f2bf(acc1);
}

// ---------------- Kernel 3: distance attention, G = P @ XN_h ---------------
// grid = (T/128, B*H); 256 threads (4 waves, 32 queries each)
__global__ __launch_bounds__(256) void k_attn(
    const float* __restrict__ Q, const float* __restrict__ K,
    const ushort* __restrict__ xnb, ushort* __restrict__ hr) {
  const int bh = blockIdx.y;
  const int b = bh >> 3, h = bh & 7;
  const int q0 = blockIdx.x * 128;
  const int tid = threadIdx.x;
  const int w = tid >> 6, l = tid & 63;
  const int l16 = l & 15, lhi = l >> 4;

  __shared__ float ks[TT];
  __shared__ float cs[TT];
  __shared__ float qs[128];
  __shared__ ushort vt[64 * 72];  // [e][72] bf16, 16B-chunk XOR swizzle

  const float* Kb = K + bh * TT;
#pragma unroll
  for (int i = 0; i < 8; i++) {
    float kv = Kb[tid + i * 256];
    ks[tid + i * 256] = kv;
    cs[tid + i * 256] = -kv * kv * CSCALE;
  }
  if (tid < 128) qs[tid] = Q[bh * TT + q0 + tid];
  __syncthreads();

  const float qv0 = qs[w * 32 + l16];
  const float qv1 = qs[w * 32 + 16 + l16];
  f32x4 acc[2][4];
  f32x4 accd[2];
#pragma unroll
  for (int g = 0; g < 2; g++) {
    accd[g] = (f32x4){0.f, 0.f, 0.f, 0.f};
#pragma unroll
    for (int c = 0; c < 4; c++) acc[g][c] = (f32x4){0.f, 0.f, 0.f, 0.f};
  }
  short8 onesbits = {0x3F80, 0x3F80, 0x3F80, 0x3F80, 0x3F80, 0x3F80, 0x3F80, 0x3F80};
  const bf16x8 ones = __builtin_bit_cast(bf16x8, onesbits);

  // B operand source: xn rows, head slice [h*64 .. h*64+63]
  const ushort* Xb = xnb + (size_t)(b * TT) * EE + h * DD;
  const int j0 = (tid >> 3) * 2;       // 0..62 (even)
  const int e0 = (tid & 7) * 8;        // 0..56

  for (int jt = 0; jt < TT; jt += 64) {
    __syncthreads();
    // stage XN tile [64j][64e] -> vt[e][j] (transposed, swizzled)
    const ushort* src = Xb + (size_t)(jt + j0) * EE + e0;
    union { uint4 v; ushort u[8]; } a0, a1;
    a0.v = *(const uint4*)src;
    a1.v = *(const uint4*)(src + EE);
#pragma unroll
    for (int i = 0; i < 8; i++) {
      int e = e0 + i;
      int off = ((j0 * 2) ^ (((e >> 3) & 7) << 4)) >> 1;  // ushort offset in row
      unsigned pack = (unsigned)a0.u[i] | ((unsigned)a1.u[i] << 16);
      *(unsigned*)&vt[e * 72 + off] = pack;
    }
    __syncthreads();

#pragma unroll
    for (int kk = 0; kk < 2; kk++) {
      // B fragments: XN[j][e], col e = c*16+l16, k-chunk = lhi*8 (+i contiguous)
      bf16x8 vf[4];
#pragma unroll
      for (int c = 0; c < 4; c++) {
        int e = c * 16 + l16;
        int offb = ((kk * 64 + lhi * 16) ^ (((e >> 3) & 7) << 4)) >> 1;
        vf[c] = *(const bf16x8*)&vt[e * 72 + offb];
      }
      const int jb = jt + kk * 32 + lhi * 8;
      float4 ka = *(const float4*)&ks[jb];
      float4 kb = *(const float4*)&ks[jb + 4];
      float4 ca = *(const float4*)&cs[jb];
      float4 cb = *(const float4*)&cs[jb + 4];
      float kv[8] = {ka.x, ka.y, ka.z, ka.w, kb.x, kb.y, kb.z, kb.w};
      float cv[8] = {ca.x, ca.y, ca.z, ca.w, cb.x, cb.y, cb.z, cb.w};
#pragma unroll
      for (int g = 0; g < 2; g++) {
        const float qv = g ? qv1 : qv0;
        bf16x8 pa;
#pragma unroll
        for (int i = 0; i < 8; i++) {
          float p = exp2f(fmaf(qv, kv[i], cv[i]));  // exp((qk/4 - k^2/8))
          pa[i] = (__bf16)p;
        }
        accd[g] = __builtin_amdgcn_mfma_f32_16x16x32_bf16(pa, ones, accd[g], 0, 0, 0);
#pragma unroll
        for (int c = 0; c < 4; c++)
          acc[g][c] = __builtin_amdgcn_mfma_f32_16x16x32_bf16(pa, vf[c], acc[g][c], 0, 0, 0);
      }
    }
  }

#pragma unroll
  for (int g = 0; g < 2; g++) {
#pragma unroll
    for (int r = 0; r < 4; r++) {
      // C/D layout: row = lhi*4 + r, col = l16; accd row-sum is col-invariant
      float rinv = 1.f / accd[g][r];
      int qrow = q0 + w * 32 + g * 16 + lhi * 4 + r;
      size_t base = ((size_t)(b * TT + qrow)) * EE + h * DD + l16;
#pragma unroll
      for (int c = 0; c < 4; c++)
        hr[base + c * 16] = f2bf(acc[g][c][r] * rinv);
    }
  }
}

// ---------------- Kernel 4: out = hr @ Wvm + x  (bf16 MFMA GEMM) -----------
// grid = (N/128=4, M/128=128); 256 threads (4 waves, 2x2 wave grid, 64x64 each)
__global__ __launch_bounds__(256) void k_merge(
    const ushort* __restrict__ hr, const ushort* __restrict__ Wmt,
    const float* __restrict__ x, float* __restrict__ out) {
  const int n0 = blockIdx.x * 128;
  const int m0 = blockIdx.y * 128;
  const int tid = threadIdx.x;
  const int w = tid >> 6, l = tid & 63;
  const int l16 = l & 15, lhi = l >> 4;
  const int wm = w >> 1, wn = w & 1;

  __shared__ ushort As[128 * 72];
  __shared__ ushort Bs[128 * 72];
  f32x4 acc[4][4];
#pragma unroll
  for (int i = 0; i < 4; i++)
#pragma unroll
    for (int j = 0; j < 4; j++) acc[i][j] = (f32x4){0.f, 0.f, 0.f, 0.f};

  const int row = tid >> 1, half = tid & 1;
  for (int k0 = 0; k0 < EE; k0 += 64) {
    __syncthreads();
    {
      const ushort* sa = hr + (size_t)(m0 + row) * EE + k0 + half * 32;
      const ushort* sb = Wmt + (size_t)(n0 + row) * EE + k0 + half * 32;
      uint4* da = (uint4*)&As[row * 72 + half * 32];
      uint4* db = (uint4*)&Bs[row * 72 + half * 32];
#pragma unroll
      for (int i = 0; i < 4; i++) da[i] = *(const uint4*)(sa + i * 8);
#pragma unroll
      for (int i = 0; i < 4; i++) db[i] = *(const uint4*)(sb + i * 8);
    }
    __syncthreads();
#pragma unroll
    for (int kk = 0; kk < 2; kk++) {
      bf16x8 af[4], bfr[4];
#pragma unroll
      for (int mi = 0; mi < 4; mi++)
        af[mi] = *(const bf16x8*)&As[(wm * 64 + mi * 16 + l16) * 72 + kk * 32 + lhi * 8];
#pragma unroll
      for (int ni = 0; ni < 4; ni++)
        bfr[ni] = *(const bf16x8*)&Bs[(wn * 64 + ni * 16 + l16) * 72 + kk * 32 + lhi * 8];
#pragma unroll
      for (int mi = 0; mi < 4; mi++)
#pragma unroll
        for (int ni = 0; ni < 4; ni++)
          acc[mi][ni] = __builtin_amdgcn_mfma_f32_16x16x32_bf16(af[mi], bfr[ni], acc[mi][ni], 0, 0, 0);
    }
  }

#pragma unroll
  for (int mi = 0; mi < 4; mi++) {
#pragma unroll
    for (int r = 0; r < 4; r++) {
      const int grow = m0 + wm * 64 + mi * 16 + lhi * 4 + r;
#pragma unroll
      for (int ni = 0; ni < 4; ni++) {
        const int gcol = n0 + wn * 64 + ni * 16 + l16;
        size_t idx = (size_t)grow * EE + gcol;
        out[idx] = acc[mi][ni][r] + x[idx];
      }
    }
  }
}

// ---------------- launch ----------------------------------------------------
extern "C" void kernel_launch(void* const* d_in, const int* in_sizes, int n_in,
                              void* d_out, int out_size, void* d_ws, size_t ws_size,
                              hipStream_t stream) {
  const float* x  = (const float*)d_in[0];
  const float* Wq = (const float*)d_in[1];
  const float* Wk = (const float*)d_in[2];
  const float* Wv = (const float*)d_in[3];
  const float* Wm = (const float*)d_in[4];
  float* out = (float*)d_out;

  char* ws = (char*)d_ws;
  // layout: Q' f32 [64][2048] | K f32 | xnb bf16 [16384][512] | hr bf16 [16384][512] | Wvmt bf16 [512][512]
  float*  Qp   = (float*)(ws);
  float*  Kp   = (float*)(ws + 524288);
  ushort* xnb  = (ushort*)(ws + 1048576);
  ushort* hrp  = (ushort*)(ws + 17825792);
  ushort* Wvmt = (ushort*)(ws + 34603008);

  k_ln<<<8 * TT, 512, 0, stream>>>(x, Wq, Wk, Qp, Kp, xnb);
  k_wvm<<<EE, 256, 0, stream>>>(Wv, Wm, Wvmt);
  k_attn<<<dim3(TT / 128, 8 * NH), 256, 0, stream>>>(Qp, Kp, xnb, hrp);
  k_merge<<<dim3(EE / 128, (8 * TT) / 128), 256, 0, stream>>>(hrp, Wvmt, x, out);
}

// Round 3
// 133.928 us; speedup vs baseline: 1.6920x; 1.2916x over previous
//
#include <hip/hip_runtime.h>

typedef __bf16 bf16x8 __attribute__((ext_vector_type(8)));
typedef short short8 __attribute__((ext_vector_type(8)));
typedef float f32x4 __attribute__((ext_vector_type(4)));

// B=8, T=2048, E=512, H=8, d=64
#define TT 2048
#define EE 512
#define NH 8
#define DD 64

#define QSCALE 0.36067376022224085f   // 0.25 * log2(e)
#define CSCALE 0.18033688011112042f   // 0.125 * log2(e)

__device__ __forceinline__ ushort f2bf(float f) {
  union { float f; unsigned u; } a; a.f = f;
  unsigned u = a.u;
  return (ushort)((u + 0x7FFFu + ((u >> 16) & 1u)) >> 16);  // RNE
}

// ---------------- Kernel 1: LayerNorm + Q',K scalars + xn (bf16) -----------
// grid = B*T blocks, 512 threads (8 waves = 8 heads)
__global__ __launch_bounds__(512) void k_ln(
    const float* __restrict__ x, const float* __restrict__ Wq,
    const float* __restrict__ Wk,
    float* __restrict__ Q, float* __restrict__ K, ushort* __restrict__ xnb) {
  const int bt = blockIdx.x;
  const int tid = threadIdx.x;
  const int lane = tid & 63, wid = tid >> 6;
  __shared__ float red[16];

  float v = x[(size_t)bt * EE + tid];
  float s = v, s2 = v * v;
#pragma unroll
  for (int o = 32; o; o >>= 1) { s += __shfl_xor(s, o); s2 += __shfl_xor(s2, o); }
  if (lane == 0) { red[wid] = s; red[8 + wid] = s2; }
  __syncthreads();
  float ts = 0.f, ts2 = 0.f;
#pragma unroll
  for (int i = 0; i < 8; i++) { ts += red[i]; ts2 += red[8 + i]; }
  const float mean = ts * (1.f / 512.f);
  const float var = ts2 * (1.f / 512.f) - mean * mean;
  const float rstd = rsqrtf(var + 1e-5f);
  const float xn = (v - mean) * rstd;
  xnb[(size_t)bt * EE + tid] = f2bf(xn);

  // wave `wid` owns head h = wid; tid = h*64 + lane indexes Wq/Wk flat
  float q = xn * Wq[tid];
  float k = xn * Wk[tid];
#pragma unroll
  for (int o = 32; o; o >>= 1) { q += __shfl_xor(q, o); k += __shfl_xor(k, o); }
  const int b = bt >> 11, t = bt & (TT - 1);
  const int bh = b * NH + wid;
  if (lane == 0) { Q[bh * TT + t] = q * QSCALE; K[bh * TT + t] = k; }
}

// ---------------- Kernel 2: Wvmt[n][k] = (Wv_h @ Wm_h)^T, bf16 -------------
__global__ __launch_bounds__(256) void k_wvm(
    const float* __restrict__ Wv, const float* __restrict__ Wm,
    ushort* __restrict__ Wvmt) {
  const int n = blockIdx.x;
  const int tid = threadIdx.x;
  const int k0 = tid, k1 = tid + 256;
  const int h0 = k0 >> 6, h1 = k1 >> 6;
  float acc0 = 0.f, acc1 = 0.f;
#pragma unroll 8
  for (int e = 0; e < 64; e++) {
    acc0 = fmaf(Wv[k0 * 64 + e], Wm[(h0 * 64 + e) * EE + n], acc0);
    acc1 = fmaf(Wv[k1 * 64 + e], Wm[(h1 * 64 + e) * EE + n], acc1);
  }
  Wvmt[n * EE + k0] = f2bf(acc0);
  Wvmt[n * EE + k1] = f2bf(acc1);
}

// ---------------- Kernel 3: distance attention, G = P @ XN_h ---------------
// grid = (T/128, B*H); 256 threads (4 waves, 32 queries each)
// double-buffered XN tile + prefetch, 1 barrier per j-tile
__global__ __launch_bounds__(256, 4) void k_attn(
    const float* __restrict__ Q, const float* __restrict__ K,
    const ushort* __restrict__ xnb, ushort* __restrict__ hr) {
  const int bh = blockIdx.y;
  const int b = bh >> 3, h = bh & 7;
  const int q0 = blockIdx.x * 128;
  const int tid = threadIdx.x;
  const int w = tid >> 6, l = tid & 63;
  const int l16 = l & 15, lhi = l >> 4;

  __shared__ float ks[TT];
  __shared__ float cs[TT];
  __shared__ float qs[128];
  __shared__ ushort vt[2][64 * 72];  // [e][72] bf16, 16B-chunk XOR swizzle

  const float* Kb = K + bh * TT;
#pragma unroll
  for (int i = 0; i < 8; i++) {
    float kv = Kb[tid + i * 256];
    ks[tid + i * 256] = kv;
    cs[tid + i * 256] = -kv * kv * CSCALE;
  }
  if (tid < 128) qs[tid] = Q[bh * TT + q0 + tid];

  // B operand source: xn rows, head slice [h*64 .. h*64+63]
  const ushort* Xb = xnb + (size_t)(b * TT) * EE + h * DD;
  const int j0 = (tid >> 3) * 2;                      // 0..62 (even)
  const int e0 = (tid & 7) * 8;                       // 0..56
  const int offc = ((j0 * 2) ^ ((tid & 7) << 4)) >> 1;  // const ushort offset in row

  union u16x8 { uint4 v; ushort u[8]; };
  // prologue: stage tile 0
  {
    u16x8 a0, a1;
    const ushort* src = Xb + (size_t)j0 * EE + e0;
    a0.v = *(const uint4*)src;
    a1.v = *(const uint4*)(src + EE);
#pragma unroll
    for (int i = 0; i < 8; i++) {
      unsigned pack = (unsigned)a0.u[i] | ((unsigned)a1.u[i] << 16);
      *(unsigned*)&vt[0][(e0 + i) * 72 + offc] = pack;
    }
  }
  __syncthreads();

  const float qv0 = qs[w * 32 + l16];
  const float qv1 = qs[w * 32 + 16 + l16];
  f32x4 acc[2][4];
  f32x4 accd[2];
#pragma unroll
  for (int g = 0; g < 2; g++) {
    accd[g] = (f32x4){0.f, 0.f, 0.f, 0.f};
#pragma unroll
    for (int c = 0; c < 4; c++) acc[g][c] = (f32x4){0.f, 0.f, 0.f, 0.f};
  }
  short8 onesbits = {0x3F80, 0x3F80, 0x3F80, 0x3F80, 0x3F80, 0x3F80, 0x3F80, 0x3F80};
  const bf16x8 ones = __builtin_bit_cast(bf16x8, onesbits);

  int p = 0;
  for (int jt = 0; jt < TT; jt += 64) {
    // prefetch next tile into registers (latency hidden under compute)
    u16x8 b0, b1;
    const bool more = (jt + 64) < TT;
    if (more) {
      const ushort* srcn = Xb + (size_t)(jt + 64 + j0) * EE + e0;
      b0.v = *(const uint4*)srcn;
      b1.v = *(const uint4*)(srcn + EE);
    }

    __builtin_amdgcn_s_setprio(1);
#pragma unroll
    for (int kk = 0; kk < 2; kk++) {
      bf16x8 vf[4];
#pragma unroll
      for (int c = 0; c < 4; c++) {
        int e = c * 16 + l16;
        int offb = ((kk * 64 + lhi * 16) ^ (((e >> 3) & 7) << 4)) >> 1;
        vf[c] = *(const bf16x8*)&vt[p][e * 72 + offb];
      }
      const int jb = jt + kk * 32 + lhi * 8;
      float4 ka = *(const float4*)&ks[jb];
      float4 kb = *(const float4*)&ks[jb + 4];
      float4 ca = *(const float4*)&cs[jb];
      float4 cb = *(const float4*)&cs[jb + 4];
      float kv[8] = {ka.x, ka.y, ka.z, ka.w, kb.x, kb.y, kb.z, kb.w};
      float cv[8] = {ca.x, ca.y, ca.z, ca.w, cb.x, cb.y, cb.z, cb.w};
#pragma unroll
      for (int g = 0; g < 2; g++) {
        const float qv = g ? qv1 : qv0;
        bf16x8 pa;
#pragma unroll
        for (int i = 0; i < 8; i++) {
          float p2 = __builtin_amdgcn_exp2f(fmaf(qv, kv[i], cv[i]));
          pa[i] = (__bf16)p2;
        }
        accd[g] = __builtin_amdgcn_mfma_f32_16x16x32_bf16(pa, ones, accd[g], 0, 0, 0);
#pragma unroll
        for (int c = 0; c < 4; c++)
          acc[g][c] = __builtin_amdgcn_mfma_f32_16x16x32_bf16(pa, vf[c], acc[g][c], 0, 0, 0);
      }
    }
    __builtin_amdgcn_s_setprio(0);

    // write prefetched tile into the other buffer
    if (more) {
#pragma unroll
      for (int i = 0; i < 8; i++) {
        unsigned pack = (unsigned)b0.u[i] | ((unsigned)b1.u[i] << 16);
        *(unsigned*)&vt[p ^ 1][(e0 + i) * 72 + offc] = pack;
      }
    }
    __syncthreads();
    p ^= 1;
  }

#pragma unroll
  for (int g = 0; g < 2; g++) {
#pragma unroll
    for (int r = 0; r < 4; r++) {
      // C/D layout: row = lhi*4 + r, col = l16; accd row-sum is col-invariant
      float rinv = 1.f / accd[g][r];
      int qrow = q0 + w * 32 + g * 16 + lhi * 4 + r;
      size_t base = ((size_t)(b * TT + qrow)) * EE + h * DD + l16;
#pragma unroll
      for (int c = 0; c < 4; c++)
        hr[base + c * 16] = f2bf(acc[g][c][r] * rinv);
    }
  }
}

// ---------------- Kernel 4: out = hr @ Wvm + x  (bf16 MFMA GEMM) -----------
// grid = (N/128=4, M/128=128); 256 threads (4 waves, 2x2 wave grid, 64x64 each)
__global__ __launch_bounds__(256) void k_merge(
    const ushort* __restrict__ hr, const ushort* __restrict__ Wmt,
    const float* __restrict__ x, float* __restrict__ out) {
  const int n0 = blockIdx.x * 128;
  const int m0 = blockIdx.y * 128;
  const int tid = threadIdx.x;
  const int w = tid >> 6, l = tid & 63;
  const int l16 = l & 15, lhi = l >> 4;
  const int wm = w >> 1, wn = w & 1;

  __shared__ ushort As[128 * 72];
  __shared__ ushort Bs[128 * 72];
  f32x4 acc[4][4];
#pragma unroll
  for (int i = 0; i < 4; i++)
#pragma unroll
    for (int j = 0; j < 4; j++) acc[i][j] = (f32x4){0.f, 0.f, 0.f, 0.f};

  const int row = tid >> 1, half = tid & 1;
  for (int k0 = 0; k0 < EE; k0 += 64) {
    __syncthreads();
    {
      const ushort* sa = hr + (size_t)(m0 + row) * EE + k0 + half * 32;
      const ushort* sb = Wmt + (size_t)(n0 + row) * EE + k0 + half * 32;
      uint4* da = (uint4*)&As[row * 72 + half * 32];
      uint4* db = (uint4*)&Bs[row * 72 + half * 32];
#pragma unroll
      for (int i = 0; i < 4; i++) da[i] = *(const uint4*)(sa + i * 8);
#pragma unroll
      for (int i = 0; i < 4; i++) db[i] = *(const uint4*)(sb + i * 8);
    }
    __syncthreads();
#pragma unroll
    for (int kk = 0; kk < 2; kk++) {
      bf16x8 af[4], bfr[4];
#pragma unroll
      for (int mi = 0; mi < 4; mi++)
        af[mi] = *(const bf16x8*)&As[(wm * 64 + mi * 16 + l16) * 72 + kk * 32 + lhi * 8];
#pragma unroll
      for (int ni = 0; ni < 4; ni++)
        bfr[ni] = *(const bf16x8*)&Bs[(wn * 64 + ni * 16 + l16) * 72 + kk * 32 + lhi * 8];
#pragma unroll
      for (int mi = 0; mi < 4; mi++)
#pragma unroll
        for (int ni = 0; ni < 4; ni++)
          acc[mi][ni] = __builtin_amdgcn_mfma_f32_16x16x32_bf16(af[mi], bfr[ni], acc[mi][ni], 0, 0, 0);
    }
  }

#pragma unroll
  for (int mi = 0; mi < 4; mi++) {
#pragma unroll
    for (int r = 0; r < 4; r++) {
      const int grow = m0 + wm * 64 + mi * 16 + lhi * 4 + r;
#pragma unroll
      for (int ni = 0; ni < 4; ni++) {
        const int gcol = n0 + wn * 64 + ni * 16 + l16;
        size_t idx = (size_t)grow * EE + gcol;
        out[idx] = acc[mi][ni][r] + x[idx];
      }
    }
  }
}

// ---------------- launch ----------------------------------------------------
extern "C" void kernel_launch(void* const* d_in, const int* in_sizes, int n_in,
                              void* d_out, int out_size, void* d_ws, size_t ws_size,
                              hipStream_t stream) {
  const float* x  = (const float*)d_in[0];
  const float* Wq = (const float*)d_in[1];
  const float* Wk = (const float*)d_in[2];
  const float* Wv = (const float*)d_in[3];
  const float* Wm = (const float*)d_in[4];
  float* out = (float*)d_out;

  char* ws = (char*)d_ws;
  // layout: Q' f32 [64][2048] | K f32 | xnb bf16 [16384][512] | hr bf16 [16384][512] | Wvmt bf16 [512][512]
  float*  Qp   = (float*)(ws);
  float*  Kp   = (float*)(ws + 524288);
  ushort* xnb  = (ushort*)(ws + 1048576);
  ushort* hrp  = (ushort*)(ws + 17825792);
  ushort* Wvmt = (ushort*)(ws + 34603008);

  k_ln<<<8 * TT, 512, 0, stream>>>(x, Wq, Wk, Qp, Kp, xnb);
  k_wvm<<<EE, 256, 0, stream>>>(Wv, Wm, Wvmt);
  k_attn<<<dim3(TT / 128, 8 * NH), 256, 0, stream>>>(Qp, Kp, xnb, hrp);
  k_merge<<<dim3(EE / 128, (8 * TT) / 128), 256, 0, stream>>>(hrp, Wvmt, x, out);
}

// Round 4
// 127.780 us; speedup vs baseline: 1.7734x; 1.0481x over previous
//
#include <hip/hip_runtime.h>

typedef __bf16 bf16x8 __attribute__((ext_vector_type(8)));
typedef short short8 __attribute__((ext_vector_type(8)));
typedef float f32x4 __attribute__((ext_vector_type(4)));

// B=8, T=2048, E=512, H=8, d=64
#define TT 2048
#define EE 512
#define NH 8
#define DD 64

#define QSCALE 0.36067376022224085f   // 0.25 * log2(e)
#define CSCALE 0.18033688011112042f   // 0.125 * log2(e)

__device__ __forceinline__ ushort f2bf(float f) {
  union { float f; unsigned u; } a; a.f = f;
  unsigned u = a.u;
  return (ushort)((u + 0x7FFFu + ((u >> 16) & 1u)) >> 16);  // RNE
}

// ---------------- Kernel 1: LayerNorm + Q',K scalars + xn (bf16) -----------
// wave per token; 256 threads = 4 tokens/block; grid = 4096
__global__ __launch_bounds__(256) void k_ln(
    const float* __restrict__ x, const float* __restrict__ Wq,
    const float* __restrict__ Wk,
    float* __restrict__ Q, float* __restrict__ K, ushort* __restrict__ xnb) {
  const int token = blockIdx.x * 4 + (threadIdx.x >> 6);
  const int l = threadIdx.x & 63;
  const float* xr = x + (size_t)token * EE + l * 8;
  float4 a = *(const float4*)xr;
  float4 c = *(const float4*)(xr + 4);
  float xv[8] = {a.x, a.y, a.z, a.w, c.x, c.y, c.z, c.w};
  float s = 0.f, s2 = 0.f;
#pragma unroll
  for (int i = 0; i < 8; i++) { s += xv[i]; s2 = fmaf(xv[i], xv[i], s2); }
#pragma unroll
  for (int o = 32; o; o >>= 1) { s += __shfl_xor(s, o); s2 += __shfl_xor(s2, o); }
  const float mean = s * (1.f / 512.f);
  const float var = s2 * (1.f / 512.f) - mean * mean;
  const float rstd = rsqrtf(var + 1e-5f);

  float xn[8];
  short8 ob;
#pragma unroll
  for (int i = 0; i < 8; i++) {
    xn[i] = (xv[i] - mean) * rstd;
    ob[i] = (short)f2bf(xn[i]);
  }
  *(short8*)(xnb + (size_t)token * EE + l * 8) = ob;

  const float* wq = Wq + l * 8;
  const float* wk = Wk + l * 8;
  float4 q1 = *(const float4*)wq, q2 = *(const float4*)(wq + 4);
  float4 k1 = *(const float4*)wk, k2 = *(const float4*)(wk + 4);
  float wqv[8] = {q1.x, q1.y, q1.z, q1.w, q2.x, q2.y, q2.z, q2.w};
  float wkv[8] = {k1.x, k1.y, k1.z, k1.w, k2.x, k2.y, k2.z, k2.w};
  float q = 0.f, k = 0.f;
#pragma unroll
  for (int i = 0; i < 8; i++) { q = fmaf(xn[i], wqv[i], q); k = fmaf(xn[i], wkv[i], k); }
#pragma unroll
  for (int o = 4; o; o >>= 1) { q += __shfl_xor(q, o); k += __shfl_xor(k, o); }
  if ((l & 7) == 0) {
    const int h = l >> 3;
    const int b = token >> 11, t = token & (TT - 1);
    const int bh = b * NH + h;
    Q[bh * TT + t] = q * QSCALE;
    K[bh * TT + t] = k;
  }
}

// ---------------- Kernel 2: Wvmt[n][k] = (Wv_h @ Wm_h)^T, bf16 -------------
__global__ __launch_bounds__(256) void k_wvm(
    const float* __restrict__ Wv, const float* __restrict__ Wm,
    ushort* __restrict__ Wvmt) {
  const int n = blockIdx.x;
  const int tid = threadIdx.x;
  const int k0 = tid, k1 = tid + 256;
  const int h0 = k0 >> 6, h1 = k1 >> 6;
  float acc0 = 0.f, acc1 = 0.f;
#pragma unroll 8
  for (int e = 0; e < 64; e++) {
    acc0 = fmaf(Wv[k0 * 64 + e], Wm[(h0 * 64 + e) * EE + n], acc0);
    acc1 = fmaf(Wv[k1 * 64 + e], Wm[(h1 * 64 + e) * EE + n], acc1);
  }
  Wvmt[n * EE + k0] = f2bf(acc0);
  Wvmt[n * EE + k1] = f2bf(acc1);
}

// ---------------- Kernel 3: distance attention, G = P @ XN_h ---------------
// grid = 512 (XCD-swizzled); 256 threads = 4 waves; each wave 64 q-rows (F=4)
__global__ __launch_bounds__(256, 2) void k_attn(
    const float* __restrict__ Q, const float* __restrict__ K,
    const ushort* __restrict__ xnb, ushort* __restrict__ hr) {
  const int sw = (blockIdx.x & 7) * 64 + (blockIdx.x >> 3);  // bijective XCD swizzle
  const int bh = sw >> 3;
  const int q0 = (sw & 7) * 256;
  const int b = bh >> 3, h = bh & 7;
  const int tid = threadIdx.x;
  const int w = tid >> 6, l = tid & 63;
  const int l16 = l & 15, lhi = l >> 4;

  __shared__ float ks[TT];
  __shared__ float cs[TT];
  __shared__ float qs[256];
  __shared__ ushort vt[2][64 * 72];  // [e][72] bf16, 16B-chunk XOR swizzle

  const float* Kb = K + bh * TT;
#pragma unroll
  for (int i = 0; i < 8; i++) {
    float kv = Kb[tid + i * 256];
    ks[tid + i * 256] = kv;
    cs[tid + i * 256] = -kv * kv * CSCALE;
  }
  qs[tid] = Q[bh * TT + q0 + tid];

  // B operand source: xn rows, head slice [h*64 .. h*64+63]
  const ushort* Xb = xnb + (size_t)(b * TT) * EE + h * DD;
  const int j0 = (tid >> 3) * 2;                        // 0..62 (even)
  const int e0 = (tid & 7) * 8;                         // 0..56
  const int offc = ((j0 * 2) ^ ((tid & 7) << 4)) >> 1;  // const ushort offset in row

  union u16x8 { uint4 v; ushort u[8]; };
  // prologue: stage tile 0
  {
    u16x8 a0, a1;
    const ushort* src = Xb + (size_t)j0 * EE + e0;
    a0.v = *(const uint4*)src;
    a1.v = *(const uint4*)(src + EE);
#pragma unroll
    for (int i = 0; i < 8; i++) {
      unsigned pack = (unsigned)a0.u[i] | ((unsigned)a1.u[i] << 16);
      *(unsigned*)&vt[0][(e0 + i) * 72 + offc] = pack;
    }
  }
  __syncthreads();

  float qv[4];
#pragma unroll
  for (int f = 0; f < 4; f++) qv[f] = qs[w * 64 + f * 16 + l16];

  f32x4 acc[4][4];
  f32x4 accd[4];
#pragma unroll
  for (int f = 0; f < 4; f++) {
    accd[f] = (f32x4){0.f, 0.f, 0.f, 0.f};
#pragma unroll
    for (int c = 0; c < 4; c++) acc[f][c] = (f32x4){0.f, 0.f, 0.f, 0.f};
  }
  short8 onesbits = {0x3F80, 0x3F80, 0x3F80, 0x3F80, 0x3F80, 0x3F80, 0x3F80, 0x3F80};
  const bf16x8 ones = __builtin_bit_cast(bf16x8, onesbits);

  int p = 0;
  for (int jt = 0; jt < TT; jt += 64) {
    // prefetch next tile into registers (latency hidden under compute)
    u16x8 b0, b1;
    const bool more = (jt + 64) < TT;
    if (more) {
      const ushort* srcn = Xb + (size_t)(jt + 64 + j0) * EE + e0;
      b0.v = *(const uint4*)srcn;
      b1.v = *(const uint4*)(srcn + EE);
    }

    __builtin_amdgcn_s_setprio(1);
#pragma unroll
    for (int kk = 0; kk < 2; kk++) {
      bf16x8 vf[4];
#pragma unroll
      for (int c = 0; c < 4; c++) {
        int e = c * 16 + l16;
        int offb = ((kk * 64 + lhi * 16) ^ (((e >> 3) & 7) << 4)) >> 1;
        vf[c] = *(const bf16x8*)&vt[p][e * 72 + offb];
      }
      const int jb = jt + kk * 32 + lhi * 8;
      float4 ka = *(const float4*)&ks[jb];
      float4 kb = *(const float4*)&ks[jb + 4];
      float4 ca = *(const float4*)&cs[jb];
      float4 cb = *(const float4*)&cs[jb + 4];
      float kv[8] = {ka.x, ka.y, ka.z, ka.w, kb.x, kb.y, kb.z, kb.w};
      float cv[8] = {ca.x, ca.y, ca.z, ca.w, cb.x, cb.y, cb.z, cb.w};
#pragma unroll
      for (int f = 0; f < 4; f++) {
        const float qf = qv[f];
        bf16x8 pa;
#pragma unroll
        for (int i = 0; i < 8; i++) {
          float p2 = __builtin_amdgcn_exp2f(fmaf(qf, kv[i], cv[i]));
          pa[i] = (__bf16)p2;
        }
        accd[f] = __builtin_amdgcn_mfma_f32_16x16x32_bf16(pa, ones, accd[f], 0, 0, 0);
#pragma unroll
        for (int c = 0; c < 4; c++)
          acc[f][c] = __builtin_amdgcn_mfma_f32_16x16x32_bf16(pa, vf[c], acc[f][c], 0, 0, 0);
      }
    }
    __builtin_amdgcn_s_setprio(0);

    // write prefetched tile into the other buffer
    if (more) {
#pragma unroll
      for (int i = 0; i < 8; i++) {
        unsigned pack = (unsigned)b0.u[i] | ((unsigned)b1.u[i] << 16);
        *(unsigned*)&vt[p ^ 1][(e0 + i) * 72 + offc] = pack;
      }
    }
    __syncthreads();
    p ^= 1;
  }

#pragma unroll
  for (int f = 0; f < 4; f++) {
#pragma unroll
    for (int r = 0; r < 4; r++) {
      // C/D layout: row = lhi*4 + r, col = l16; accd row-sum is col-invariant
      float rinv = 1.f / accd[f][r];
      int qrow = q0 + w * 64 + f * 16 + lhi * 4 + r;
      size_t base = ((size_t)(b * TT + qrow)) * EE + h * DD + l16;
#pragma unroll
      for (int c = 0; c < 4; c++)
        hr[base + c * 16] = f2bf(acc[f][c][r] * rinv);
    }
  }
}

// ---------------- Kernel 4: out = hr @ Wvm + x  (bf16 MFMA GEMM) -----------
// grid = (4, 128); 256 threads (4 waves, 2x2 wave grid, 64x64 each)
// double-buffered LDS + register prefetch, 1 barrier per k-step
__global__ __launch_bounds__(256, 2) void k_merge(
    const ushort* __restrict__ hr, const ushort* __restrict__ Wmt,
    const float* __restrict__ x, float* __restrict__ out) {
  const int n0 = blockIdx.x * 128;
  const int m0 = blockIdx.y * 128;
  const int tid = threadIdx.x;
  const int w = tid >> 6, l = tid & 63;
  const int l16 = l & 15, lhi = l >> 4;
  const int wm = w >> 1, wn = w & 1;

  __shared__ ushort As[2][128 * 72];
  __shared__ ushort Bs[2][128 * 72];
  f32x4 acc[4][4];
#pragma unroll
  for (int i = 0; i < 4; i++)
#pragma unroll
    for (int j = 0; j < 4; j++) acc[i][j] = (f32x4){0.f, 0.f, 0.f, 0.f};

  const int row = tid >> 1, half = tid & 1;
  const ushort* sa0 = hr + (size_t)(m0 + row) * EE + half * 32;
  const ushort* sb0 = Wmt + (size_t)(n0 + row) * EE + half * 32;

  // prologue: stage k-step 0
  {
    uint4* da = (uint4*)&As[0][row * 72 + half * 32];
    uint4* db = (uint4*)&Bs[0][row * 72 + half * 32];
#pragma unroll
    for (int i = 0; i < 4; i++) da[i] = *(const uint4*)(sa0 + i * 8);
#pragma unroll
    for (int i = 0; i < 4; i++) db[i] = *(const uint4*)(sb0 + i * 8);
  }
  __syncthreads();

  int p = 0;
  for (int k0 = 0; k0 < EE; k0 += 64) {
    const bool more = (k0 + 64) < EE;
    uint4 pa[4], pb[4];
    if (more) {
#pragma unroll
      for (int i = 0; i < 4; i++) pa[i] = *(const uint4*)(sa0 + k0 + 64 + i * 8);
#pragma unroll
      for (int i = 0; i < 4; i++) pb[i] = *(const uint4*)(sb0 + k0 + 64 + i * 8);
    }
#pragma unroll
    for (int kk = 0; kk < 2; kk++) {
      bf16x8 af[4], bfr[4];
#pragma unroll
      for (int mi = 0; mi < 4; mi++)
        af[mi] = *(const bf16x8*)&As[p][(wm * 64 + mi * 16 + l16) * 72 + kk * 32 + lhi * 8];
#pragma unroll
      for (int ni = 0; ni < 4; ni++)
        bfr[ni] = *(const bf16x8*)&Bs[p][(wn * 64 + ni * 16 + l16) * 72 + kk * 32 + lhi * 8];
#pragma unroll
      for (int mi = 0; mi < 4; mi++)
#pragma unroll
        for (int ni = 0; ni < 4; ni++)
          acc[mi][ni] = __builtin_amdgcn_mfma_f32_16x16x32_bf16(af[mi], bfr[ni], acc[mi][ni], 0, 0, 0);
    }
    if (more) {
      uint4* da = (uint4*)&As[p ^ 1][row * 72 + half * 32];
      uint4* db = (uint4*)&Bs[p ^ 1][row * 72 + half * 32];
#pragma unroll
      for (int i = 0; i < 4; i++) da[i] = pa[i];
#pragma unroll
      for (int i = 0; i < 4; i++) db[i] = pb[i];
    }
    __syncthreads();
    p ^= 1;
  }

#pragma unroll
  for (int mi = 0; mi < 4; mi++) {
#pragma unroll
    for (int r = 0; r < 4; r++) {
      const int grow = m0 + wm * 64 + mi * 16 + lhi * 4 + r;
#pragma unroll
      for (int ni = 0; ni < 4; ni++) {
        const int gcol = n0 + wn * 64 + ni * 16 + l16;
        size_t idx = (size_t)grow * EE + gcol;
        out[idx] = acc[mi][ni][r] + x[idx];
      }
    }
  }
}

// ---------------- launch ----------------------------------------------------
extern "C" void kernel_launch(void* const* d_in, const int* in_sizes, int n_in,
                              void* d_out, int out_size, void* d_ws, size_t ws_size,
                              hipStream_t stream) {
  const float* x  = (const float*)d_in[0];
  const float* Wq = (const float*)d_in[1];
  const float* Wk = (const float*)d_in[2];
  const float* Wv = (const float*)d_in[3];
  const float* Wm = (const float*)d_in[4];
  float* out = (float*)d_out;

  char* ws = (char*)d_ws;
  // layout: Q' f32 [64][2048] | K f32 | xnb bf16 [16384][512] | hr bf16 [16384][512] | Wvmt bf16 [512][512]
  float*  Qp   = (float*)(ws);
  float*  Kp   = (float*)(ws + 524288);
  ushort* xnb  = (ushort*)(ws + 1048576);
  ushort* hrp  = (ushort*)(ws + 17825792);
  ushort* Wvmt = (ushort*)(ws + 34603008);

  k_ln<<<4096, 256, 0, stream>>>(x, Wq, Wk, Qp, Kp, xnb);
  k_wvm<<<EE, 256, 0, stream>>>(Wv, Wm, Wvmt);
  k_attn<<<512, 256, 0, stream>>>(Qp, Kp, xnb, hrp);
  k_merge<<<dim3(EE / 128, (8 * TT) / 128), 256, 0, stream>>>(hrp, Wvmt, x, out);
}